// Round 10
// baseline (37.738 us; speedup 1.0000x reference)
//
#include <hip/hip_runtime.h>
#include <hip/hip_fp16.h>
#include <stdint.h>

#define TOKENS 2048
#define DIM    2048
#define GROUP  128
#define NGK    16   // K-groups per row

typedef __attribute__((ext_vector_type(4)))  int   i32x4;
typedef __attribute__((ext_vector_type(16))) int   i32x16;
typedef __attribute__((ext_vector_type(4)))  float f32x4;
typedef __attribute__((ext_vector_type(16))) float f32x16;

// ---------------- quantization (int8 q/4 + per-group scale*4) ----------------

__device__ __forceinline__ float group32_sum(float v) {
#pragma unroll
  for (int off = 16; off > 0; off >>= 1)
    v += __shfl_xor(v, off, 64);
  return v;
}

// nearest merged-grid point in q/4 units: ints {-7..7} U +-{12,16,24,32,48,64,96}
__device__ __forceinline__ float nearest_q4(float u) {
  float qi = fminf(fmaxf(rintf(u), -7.f), 7.f);
  float a = fabsf(u);
  float m = a <= 14.f ? 12.f : a <= 20.f ? 16.f : a <= 28.f ? 24.f
          : a <= 40.f ? 32.f : a <= 56.f ? 48.f : a <= 80.f ? 64.f : 96.f;
  float qo = copysignf(m, u);
  return (fabsf(u - qo) < fabsf(u - qi)) ? qo : qi;   // int grid wins ties
}

__global__ __launch_bounds__(256) void quant2_kernel(
    const float* __restrict__ x, const float* __restrict__ w,
    int8_t* __restrict__ q8,          // qx (4MB) ++ qw (4MB), values = grid/4
    float* __restrict__ ssxT,         // [16][2048]  scale*4, transposed
    float* __restrict__ sswT) {       // [16][2048]
  const int wid  = threadIdx.x >> 6;
  const int lane = threadIdx.x & 63;
  const int l    = lane & 31;
  const int g    = blockIdx.x * 8 + wid * 2 + (lane >> 5);
  const int NG1  = TOKENS * DIM / GROUP;   // 32768

  const float alpha = (g < NG1) ? 0.9f : 1.0f;
  const float* src  = (g < NG1) ? x : w;
  const int grow    = (g < NG1) ? g : g - NG1;
  const size_t sbase = (size_t)grow * GROUP + l * 4;

  const float4 v = *reinterpret_cast<const float4*>(src + sbase);

  const float mean = group32_sum(v.x + v.y + v.z + v.w) * (1.0f / 128.0f);
  const float d0 = v.x - mean, d1 = v.y - mean, d2 = v.z - mean, d3 = v.w - mean;
  const float var = group32_sum(d0 * d0 + d1 * d1 + d2 * d2 + d3 * d3) *
                    (1.0f / 127.0f);
  const float scale = (fabsf(mean) + 3.0f * sqrtf(var)) * alpha / 28.0f;
  const float rs4 = 0.25f / scale;          // to q/4 units

  float q0 = nearest_q4(v.x * rs4);
  float q1 = nearest_q4(v.y * rs4);
  float q2 = nearest_q4(v.z * rs4);
  float q3 = nearest_q4(v.w * rs4);
  // victim masking: outlier (|q/4|>8) zeroes its pair partner
  if (fabsf(q0) > 8.0f)      q1 = 0.0f;
  else if (fabsf(q1) > 8.0f) q0 = 0.0f;
  if (fabsf(q2) > 8.0f)      q3 = 0.0f;
  else if (fabsf(q3) > 8.0f) q2 = 0.0f;

  const int p = ((int)q0 & 255) | (((int)q1 & 255) << 8) |
                (((int)q2 & 255) << 16) | (((int)q3 & 255) << 24);
  reinterpret_cast<int*>(q8)[(size_t)g * 32 + l] = p;

  if (l == 0) {
    const float ss = 4.0f * scale;
    if (g < NG1) ssxT[(grow & 15) * 2048 + (grow >> 4)] = ss;
    else         sswT[(grow & 15) * 2048 + (grow >> 4)] = ss;
  }
}

// ---------------- GEMM: C = sum_g ssx*ssw*(int8 group dot) ----------------
// BM=128, BN=64, BK=128 (one scale group). 256 thr = 4 waves (wr x wz):
// wave tile 64x64 = 2x2 of 32x32 (16 LDS reads -> 16 MFMA, ratio 1.0 —
// down from R9's 1.5, the tallest pipe), 2-way split-K over the 4 K=32
// slices (R5's proven epilogue). Registers: accf 64 + acci 64 + frags
// ~50 = ~180 < 256-VGPR cap at 2 waves/SIMD (256-thr block, 2 blocks/CU)
// -> no spill (R7/R8 lesson: 512-thr blocks cap at 128 and spill).
// 2-deep pipeline, counted vmcnt(6); XOR swizzle both-sides; XCD 4x16.

__device__ __forceinline__ void gload_lds16(const int8_t* g, char* l) {
  __builtin_amdgcn_global_load_lds(
      (__attribute__((address_space(1))) uint32_t*)g,
      (__attribute__((address_space(3))) uint32_t*)l, 16, 0, 0);
}

__global__ __launch_bounds__(256, 2) void gemm_kernel(
    const int8_t* __restrict__ Aq, const int8_t* __restrict__ Bq,
    const float* __restrict__ ssxT, const float* __restrict__ sswT,
    float* __restrict__ C) {
  // 2 stages x (A 16K + B 8K) = 48 KB, + scales 12 KB = 60 KB (2 blocks/CU)
  __shared__ char lds_raw[2 * 24576 + 12288];
  float* ssx_l = (float*)(lds_raw + 49152);          // [16][128]
  float* ssw_l = (float*)(lds_raw + 49152 + 8192);   // [16][64]

  const int tid  = threadIdx.x;
  const int lane = tid & 63;
  const int wid  = tid >> 6;       // 0..3
  const int wr   = wid >> 1;       // 0..1 (64-row half)
  const int wz   = wid & 1;        // 0..1 (K-half: ks = 2*wz..2*wz+1)
  const int r31  = lane & 31;
  const int hi   = lane >> 5;

  // XCD c owns bm in [(c&3)*4,+4), bn in [(c>>2)*16,+16): ~3 MB panels -> L2
  const int bid = blockIdx.x;
  const int c   = bid & 7;
  const int idx = bid >> 3;                   // 0..63
  const int bm  = ((c & 3) << 2) + (idx >> 4);    // 0..15
  const int bn  = ((c >> 2) << 4) + (idx & 15);   // 0..31

  const int8_t* gA = Aq + (size_t)(bm * 128) * DIM;
  const int8_t* gB = Bq + (size_t)(bn * 64) * DIM;

  auto stage = [&](char* buf, int g) {
#pragma unroll
    for (int i = 0; i < 4; ++i) {     // A: 128x128 i8 = 16 KB
      int P   = (i * 256 + tid) * 16;
      int row = P >> 7;
      int cb  = (P & 127) ^ ((row & 7) << 4);
      gload_lds16(gA + (size_t)row * DIM + g * 128 + cb, buf + P);
    }
#pragma unroll
    for (int i = 0; i < 2; ++i) {     // B: 64x128 i8 = 8 KB
      int P   = (i * 256 + tid) * 16;
      int row = P >> 7;
      int cb  = (P & 127) ^ ((row & 7) << 4);
      gload_lds16(gB + (size_t)row * DIM + g * 128 + cb, buf + 16384 + P);
    }
  };

  // ---- stage scale tables, then full drain (keeps manual vmcnt exact) ----
#pragma unroll
  for (int i = 0; i < 2; ++i) {       // ssx: 2048 floats
    int f = (i * 256 + tid) * 4;
    *reinterpret_cast<f32x4*>(&ssx_l[f]) =
        *reinterpret_cast<const f32x4*>(&ssxT[(f >> 7) * 2048 + bm * 128 + (f & 127)]);
  }
  {                                   // ssw: 1024 floats
    int f = tid * 4;
    *reinterpret_cast<f32x4*>(&ssw_l[f]) =
        *reinterpret_cast<const f32x4*>(&sswT[(f >> 6) * 2048 + bn * 64 + (f & 63)]);
  }
  __syncthreads();                    // drain scale loads + publish LDS

  f32x16 accf[2][2] = {};
  const i32x16 zacc = {};

  auto compute = [&](const char* buf, int gk) {
    const char* cA = buf;
    const char* cB = buf + 16384;
    i32x16 acci[2][2];
#pragma unroll
    for (int s = 0; s < 2; ++s) {
      const int ks = wz * 2 + s;      // this wave's K=32 slice
      const int cb = ks * 32 + hi * 16;
      i32x4 af[2], bf[2];
#pragma unroll
      for (int mt = 0; mt < 2; ++mt) {
        int row = wr * 64 + mt * 32 + r31;
        int pc  = cb ^ ((row & 7) << 4);
        af[mt] = *reinterpret_cast<const i32x4*>(cA + (row << 7) + pc);
      }
#pragma unroll
      for (int nt = 0; nt < 2; ++nt) {
        int row = nt * 32 + r31;
        int pc  = cb ^ ((row & 7) << 4);
        bf[nt] = *reinterpret_cast<const i32x4*>(cB + (row << 7) + pc);
      }
      __builtin_amdgcn_s_setprio(1);
#pragma unroll
      for (int mt = 0; mt < 2; ++mt)
#pragma unroll
        for (int nt = 0; nt < 2; ++nt)
          acci[mt][nt] = __builtin_amdgcn_mfma_i32_32x32x32_i8(
              af[mt], bf[nt], s == 0 ? zacc : acci[mt][nt], 0, 0, 0);
      __builtin_amdgcn_s_setprio(0);
    }
    // accf += ssx[row] * ssw[col] * float(acci)  (partial group dot * scale)
    float sw[2];
#pragma unroll
    for (int nt = 0; nt < 2; ++nt)
      sw[nt] = ssw_l[gk * 64 + nt * 32 + r31];
#pragma unroll
    for (int mt = 0; mt < 2; ++mt)
#pragma unroll
      for (int q = 0; q < 4; ++q) {
        f32x4 sx = *reinterpret_cast<const f32x4*>(
            &ssx_l[gk * 128 + wr * 64 + mt * 32 + 8 * q + 4 * hi]);
#pragma unroll
        for (int nt = 0; nt < 2; ++nt)
#pragma unroll
          for (int e = 0; e < 4; ++e)
            accf[mt][nt][q * 4 + e] +=
                sx[e] * (sw[nt] * (float)acci[mt][nt][q * 4 + e]);
      }
  };

  char* S0 = lds_raw;
  char* S1 = lds_raw + 24576;

  stage(S0, 0);
  for (int j = 0; j < NGK; ++j) {     // 16 K-groups
    if (j + 1 < NGK) {
      stage((j & 1) ? S0 : S1, j + 1);
      asm volatile("s_waitcnt vmcnt(6)" ::: "memory");   // group j's loads done
    } else {
      asm volatile("s_waitcnt vmcnt(0)" ::: "memory");
    }
    __builtin_amdgcn_s_barrier();
    compute((j & 1) ? S1 : S0, j);
    __builtin_amdgcn_s_barrier();
  }

  // ---- 2-way split-K reduction over wz (R5 pattern), then store ----
  __syncthreads();                    // pipeline LDS now dead
  float* red = (float*)lds_raw;       // 32 KB used
  if (wz == 1) {
#pragma unroll
    for (int mt = 0; mt < 2; ++mt)
#pragma unroll
      for (int nt = 0; nt < 2; ++nt) {
        const int t = mt * 2 + nt;
#pragma unroll
        for (int q = 0; q < 4; ++q) {
          f32x4 v;
          v.x = accf[mt][nt][q * 4 + 0];
          v.y = accf[mt][nt][q * 4 + 1];
          v.z = accf[mt][nt][q * 4 + 2];
          v.w = accf[mt][nt][q * 4 + 3];
          *reinterpret_cast<f32x4*>(
              red + (size_t)((wr * 16 + t * 4 + q) * 64 + lane) * 4) = v;
        }
      }
  }
  __syncthreads();
  if (wz == 0) {
    const int crow0 = bm * 128 + wr * 64 + 4 * hi;
    const int ccol0 = bn * 64 + r31;
#pragma unroll
    for (int mt = 0; mt < 2; ++mt)
#pragma unroll
      for (int nt = 0; nt < 2; ++nt) {
        const int t = mt * 2 + nt;
#pragma unroll
        for (int q = 0; q < 4; ++q) {
          f32x4 v = *reinterpret_cast<const f32x4*>(
              red + (size_t)((wr * 16 + t * 4 + q) * 64 + lane) * 4);
          accf[mt][nt][q * 4 + 0] += v.x;
          accf[mt][nt][q * 4 + 1] += v.y;
          accf[mt][nt][q * 4 + 2] += v.z;
          accf[mt][nt][q * 4 + 3] += v.w;
        }
#pragma unroll
        for (int r = 0; r < 16; ++r) {
          int row = crow0 + mt * 32 + (r & 3) + 8 * (r >> 2);
          int col = ccol0 + nt * 32;
          C[(size_t)row * DIM + col] = accf[mt][nt][r];
        }
      }
  }
}

// ---------------- launch ----------------

extern "C" void kernel_launch(void* const* d_in, const int* in_sizes, int n_in,
                              void* d_out, int out_size, void* d_ws,
                              size_t ws_size, hipStream_t stream) {
  const float* x = (const float*)d_in[0];
  const float* w = (const float*)d_in[1];
  float* out = (float*)d_out;

  int8_t* qx   = (int8_t*)d_ws;                         // 4 MB
  int8_t* qw   = qx + (size_t)TOKENS * DIM;             // 4 MB
  float*  ssxT = (float*)(qw + (size_t)DIM * DIM);      // 128 KB
  float*  sswT = ssxT + NGK * 2048;                     // 128 KB

  const int ngroups = 2 * TOKENS * DIM / GROUP;         // 65536
  quant2_kernel<<<ngroups / 8, 256, 0, stream>>>(x, w, qx, ssxT, sswT);

  gemm_kernel<<<512, 256, 0, stream>>>(qx, qw, ssxT, sswT, out);
}

// Round 11
// 35.508 us; speedup vs baseline: 1.0628x; 1.0628x over previous
//
#include <hip/hip_runtime.h>
#include <hip/hip_fp16.h>
#include <stdint.h>

#define TOKENS 2048
#define DIM    2048
#define GROUP  128
#define NGK    16   // K-groups per row

typedef _Float16 half_t;
typedef __attribute__((ext_vector_type(4)))  _Float16 f16x4;
typedef __attribute__((ext_vector_type(8)))  _Float16 f16x8;
typedef __attribute__((ext_vector_type(4)))  int   i32x4;
typedef __attribute__((ext_vector_type(16))) int   i32x16;
typedef __attribute__((ext_vector_type(4)))  float f32x4;
typedef __attribute__((ext_vector_type(16))) float f32x16;

// ---------------- quantization (int8 q/4 + per-group fp16 scale*4) ----------------

__device__ __forceinline__ float group32_sum(float v) {
#pragma unroll
  for (int off = 16; off > 0; off >>= 1)
    v += __shfl_xor(v, off, 64);
  return v;
}

// nearest merged-grid point in q/4 units: ints {-7..7} U +-{12,16,24,32,48,64,96}
__device__ __forceinline__ float nearest_q4(float u) {
  float qi = fminf(fmaxf(rintf(u), -7.f), 7.f);
  float a = fabsf(u);
  float m = a <= 14.f ? 12.f : a <= 20.f ? 16.f : a <= 28.f ? 24.f
          : a <= 40.f ? 32.f : a <= 56.f ? 48.f : a <= 80.f ? 64.f : 96.f;
  float qo = copysignf(m, u);
  return (fabsf(u - qo) < fabsf(u - qi)) ? qo : qi;   // int grid wins ties
}

__global__ __launch_bounds__(256) void quant2_kernel(
    const float* __restrict__ x, const float* __restrict__ w,
    int8_t* __restrict__ q8,          // qx (4MB) ++ qw (4MB), values = grid/4
    half_t* __restrict__ ssxT,        // [16][2048]  scale*4 (fp16), transposed
    half_t* __restrict__ sswT) {      // [16][2048]
  const int wid  = threadIdx.x >> 6;
  const int lane = threadIdx.x & 63;
  const int l    = lane & 31;
  const int g    = blockIdx.x * 8 + wid * 2 + (lane >> 5);
  const int NG1  = TOKENS * DIM / GROUP;   // 32768

  const float alpha = (g < NG1) ? 0.9f : 1.0f;
  const float* src  = (g < NG1) ? x : w;
  const int grow    = (g < NG1) ? g : g - NG1;
  const size_t sbase = (size_t)grow * GROUP + l * 4;

  const float4 v = *reinterpret_cast<const float4*>(src + sbase);

  const float mean = group32_sum(v.x + v.y + v.z + v.w) * (1.0f / 128.0f);
  const float d0 = v.x - mean, d1 = v.y - mean, d2 = v.z - mean, d3 = v.w - mean;
  const float var = group32_sum(d0 * d0 + d1 * d1 + d2 * d2 + d3 * d3) *
                    (1.0f / 127.0f);
  const float scale = (fabsf(mean) + 3.0f * sqrtf(var)) * alpha / 28.0f;
  const float rs4 = 0.25f / scale;          // to q/4 units

  float q0 = nearest_q4(v.x * rs4);
  float q1 = nearest_q4(v.y * rs4);
  float q2 = nearest_q4(v.z * rs4);
  float q3 = nearest_q4(v.w * rs4);
  // victim masking: outlier (|q/4|>8) zeroes its pair partner
  if (fabsf(q0) > 8.0f)      q1 = 0.0f;
  else if (fabsf(q1) > 8.0f) q0 = 0.0f;
  if (fabsf(q2) > 8.0f)      q3 = 0.0f;
  else if (fabsf(q3) > 8.0f) q2 = 0.0f;

  const int p = ((int)q0 & 255) | (((int)q1 & 255) << 8) |
                (((int)q2 & 255) << 16) | (((int)q3 & 255) << 24);
  reinterpret_cast<int*>(q8)[(size_t)g * 32 + l] = p;

  if (l == 0) {
    const half_t ss = (half_t)(4.0f * scale);
    if (g < NG1) ssxT[(grow & 15) * 2048 + (grow >> 4)] = ss;
    else         sswT[(grow & 15) * 2048 + (grow >> 4)] = ss;
  }
}

// ---------------- GEMM: C = sum_g ssx*ssw*(int8 group dot) ----------------
// R9 geometry (proven 33.9 us total), one lever changed: 3-deep pipeline.
// BM=128, BN=64, BK=128 (one scale group). 256 thr = 4 waves (wr,wc), wave
// tile 64x32 -> accf[2]+acci[2] = 64 reg accumulator, no spill. Grid 512 =
// 2 blocks/CU. 3-deep pipeline with vmcnt(12): each stage's 6 loads get TWO
// group-intervals to land (HBM-miss latency ~900cy > 1 interval; R3 showed
// +4us for 2->3 deep). LDS 3x24 KB + fp16 scale tables 6 KB = 78 KB -> still
// 2 blocks/CU (fp16 scales: <=2^-11 rel rounding, ~5e-3 output error, safe
// vs 0.091). XOR swizzle both-sides; XCD 4x16 chunks; no split-K.

__device__ __forceinline__ void gload_lds16(const int8_t* g, char* l) {
  __builtin_amdgcn_global_load_lds(
      (__attribute__((address_space(1))) uint32_t*)g,
      (__attribute__((address_space(3))) uint32_t*)l, 16, 0, 0);
}

__global__ __launch_bounds__(256, 2) void gemm_kernel(
    const int8_t* __restrict__ Aq, const int8_t* __restrict__ Bq,
    const half_t* __restrict__ ssxT, const half_t* __restrict__ sswT,
    float* __restrict__ C) {
  // 3 stages x (A 16K + B 8K) = 72 KB, + fp16 scales 6 KB = 78 KB
  __shared__ char lds_raw[3 * 24576 + 6144];
  half_t* ssx_l = (half_t*)(lds_raw + 73728);          // [16][128] fp16
  half_t* ssw_l = (half_t*)(lds_raw + 73728 + 4096);   // [16][64]  fp16

  const int tid  = threadIdx.x;
  const int lane = tid & 63;
  const int wid  = tid >> 6;       // 0..3
  const int wr   = wid >> 1;       // 0..1 (64 rows)
  const int wc   = wid & 1;        // 0..1 (32 cols)
  const int r31  = lane & 31;
  const int hi   = lane >> 5;

  // XCD c owns bm in [(c&3)*4,+4), bn in [(c>>2)*16,+16): ~3 MB panels -> L2
  const int bid = blockIdx.x;
  const int c   = bid & 7;
  const int idx = bid >> 3;                   // 0..63
  const int bm  = ((c & 3) << 2) + (idx >> 4);    // 0..15
  const int bn  = ((c >> 2) << 4) + (idx & 15);   // 0..31

  const int8_t* gA = Aq + (size_t)(bm * 128) * DIM;
  const int8_t* gB = Bq + (size_t)(bn * 64) * DIM;

  auto stage = [&](char* buf, int g) {
#pragma unroll
    for (int i = 0; i < 4; ++i) {     // A: 128x128 i8 = 16 KB
      int P   = (i * 256 + tid) * 16;
      int row = P >> 7;
      int cb  = (P & 127) ^ ((row & 7) << 4);
      gload_lds16(gA + (size_t)row * DIM + g * 128 + cb, buf + P);
    }
#pragma unroll
    for (int i = 0; i < 2; ++i) {     // B: 64x128 i8 = 8 KB
      int P   = (i * 256 + tid) * 16;
      int row = P >> 7;
      int cb  = (P & 127) ^ ((row & 7) << 4);
      gload_lds16(gB + (size_t)row * DIM + g * 128 + cb, buf + 16384 + P);
    }
  };

  // ---- stage fp16 scale tables, full drain (keeps manual vmcnt exact) ----
  {                                   // ssx: 2048 halfs, 16 B/thread
    int f = tid * 8;                  // gk = f>>7, r = f&127 (8-aligned)
    *reinterpret_cast<f16x8*>(&ssx_l[f]) =
        *reinterpret_cast<const f16x8*>(&ssxT[(f >> 7) * 2048 + bm * 128 + (f & 127)]);
  }
  if (tid < 128) {                    // ssw: 1024 halfs
    int f = tid * 8;                  // gk = f>>6, r = f&63
    *reinterpret_cast<f16x8*>(&ssw_l[f]) =
        *reinterpret_cast<const f16x8*>(&sswT[(f >> 6) * 2048 + bn * 64 + (f & 63)]);
  }
  __syncthreads();                    // drain scale loads + publish LDS

  f32x16 accf[2] = {};
  const i32x16 zacc = {};

  auto compute = [&](const char* buf, int gk) {
    const char* cA = buf;
    const char* cB = buf + 16384;
    i32x16 acci[2];
#pragma unroll
    for (int ks = 0; ks < 4; ++ks) {
      const int cb = ks * 32 + hi * 16;
      i32x4 af[2], bf;
#pragma unroll
      for (int mt = 0; mt < 2; ++mt) {
        int row = wr * 64 + mt * 32 + r31;
        int pc  = cb ^ ((row & 7) << 4);
        af[mt] = *reinterpret_cast<const i32x4*>(cA + (row << 7) + pc);
      }
      {
        int row = wc * 32 + r31;
        int pc  = cb ^ ((row & 7) << 4);
        bf = *reinterpret_cast<const i32x4*>(cB + (row << 7) + pc);
      }
      __builtin_amdgcn_s_setprio(1);
#pragma unroll
      for (int mt = 0; mt < 2; ++mt)
        acci[mt] = __builtin_amdgcn_mfma_i32_32x32x32_i8(
            af[mt], bf, ks == 0 ? zacc : acci[mt], 0, 0, 0);
      __builtin_amdgcn_s_setprio(0);
    }
    // accf += ssx[row] * ssw[col] * float(acci)
    const float sw = (float)ssw_l[gk * 64 + wc * 32 + r31];
#pragma unroll
    for (int mt = 0; mt < 2; ++mt)
#pragma unroll
      for (int q = 0; q < 4; ++q) {
        f16x4 sxh = *reinterpret_cast<const f16x4*>(
            &ssx_l[gk * 128 + wr * 64 + mt * 32 + 8 * q + 4 * hi]);
#pragma unroll
        for (int e = 0; e < 4; ++e)
          accf[mt][q * 4 + e] +=
              (float)sxh[e] * (sw * (float)acci[mt][q * 4 + e]);
      }
  };

  char* S0 = lds_raw;
  char* S1 = lds_raw + 24576;
  char* S2 = lds_raw + 49152;

  stage(S0, 0);
  stage(S1, 1);

  auto iter = [&](int j, const char* cbuf, char* sbuf) {
    if (j <= 13) {
      stage(sbuf, j + 2);
      asm volatile("s_waitcnt vmcnt(12)" ::: "memory");  // group j's loads done
    } else if (j == 14) {
      asm volatile("s_waitcnt vmcnt(6)" ::: "memory");
    } else {
      asm volatile("s_waitcnt vmcnt(0)" ::: "memory");
    }
    __builtin_amdgcn_s_barrier();
    compute(cbuf, j);
    __builtin_amdgcn_s_barrier();
  };

  // buffers: S0:{0,3,..,15}, S1:{1,4,..,13}, S2:{2,5,..,14}
  for (int t = 0; t < 12; t += 3) {   // j = 0..11
    iter(t + 0, S0, S2);
    iter(t + 1, S1, S0);
    iter(t + 2, S2, S1);
  }
  iter(12, S0, S2);                   // stages 14
  iter(13, S1, S0);                   // stages 15
  iter(14, S2, S1);                   // vmcnt(6)
  iter(15, S0, S2);                   // vmcnt(0)

  // ---- direct C write (no split-K) ----
  const int crow0 = bm * 128 + wr * 64 + 4 * hi;
  const int ccol  = bn * 64 + wc * 32 + r31;
#pragma unroll
  for (int mt = 0; mt < 2; ++mt)
#pragma unroll
    for (int r = 0; r < 16; ++r) {
      int row = crow0 + mt * 32 + (r & 3) + 8 * (r >> 2);
      C[(size_t)row * DIM + ccol] = accf[mt][r];
    }
}

// ---------------- launch ----------------

extern "C" void kernel_launch(void* const* d_in, const int* in_sizes, int n_in,
                              void* d_out, int out_size, void* d_ws,
                              size_t ws_size, hipStream_t stream) {
  const float* x = (const float*)d_in[0];
  const float* w = (const float*)d_in[1];
  float* out = (float*)d_out;

  int8_t* qx   = (int8_t*)d_ws;                         // 4 MB
  int8_t* qw   = qx + (size_t)TOKENS * DIM;             // 4 MB
  half_t* ssxT = (half_t*)(qw + (size_t)DIM * DIM);     // 64 KB
  half_t* sswT = ssxT + NGK * 2048;                     // 64 KB

  const int ngroups = 2 * TOKENS * DIM / GROUP;         // 65536
  quant2_kernel<<<ngroups / 8, 256, 0, stream>>>(x, w, qx, ssxT, sswT);

  gemm_kernel<<<512, 256, 0, stream>>>(qx, qw, ssxT, sswT, out);
}

// Round 12
// 34.632 us; speedup vs baseline: 1.0897x; 1.0253x over previous
//
#include <hip/hip_runtime.h>
#include <hip/hip_fp16.h>
#include <stdint.h>

#define TOKENS 2048
#define DIM    2048
#define GROUP  128
#define NGK    16   // K-groups per row

typedef __attribute__((ext_vector_type(4)))  int   i32x4;
typedef __attribute__((ext_vector_type(16))) int   i32x16;
typedef __attribute__((ext_vector_type(4)))  float f32x4;
typedef __attribute__((ext_vector_type(16))) float f32x16;

// ---------------- quantization (int8 q/4 + per-group scale*4) ----------------

__device__ __forceinline__ float group32_sum(float v) {
#pragma unroll
  for (int off = 16; off > 0; off >>= 1)
    v += __shfl_xor(v, off, 64);
  return v;
}

// nearest merged-grid point in q/4 units: ints {-7..7} U +-{12,16,24,32,48,64,96}
__device__ __forceinline__ float nearest_q4(float u) {
  float qi = fminf(fmaxf(rintf(u), -7.f), 7.f);
  float a = fabsf(u);
  float m = a <= 14.f ? 12.f : a <= 20.f ? 16.f : a <= 28.f ? 24.f
          : a <= 40.f ? 32.f : a <= 56.f ? 48.f : a <= 80.f ? 64.f : 96.f;
  float qo = copysignf(m, u);
  return (fabsf(u - qo) < fabsf(u - qi)) ? qo : qi;   // int grid wins ties
}

__global__ __launch_bounds__(256) void quant2_kernel(
    const float* __restrict__ x, const float* __restrict__ w,
    int8_t* __restrict__ q8,          // qx (4MB) ++ qw (4MB), values = grid/4
    float* __restrict__ ssxT,         // [16][2048]  scale*4, transposed
    float* __restrict__ sswT) {       // [16][2048]
  const int wid  = threadIdx.x >> 6;
  const int lane = threadIdx.x & 63;
  const int l    = lane & 31;
  const int g    = blockIdx.x * 8 + wid * 2 + (lane >> 5);
  const int NG1  = TOKENS * DIM / GROUP;   // 32768

  const float alpha = (g < NG1) ? 0.9f : 1.0f;
  const float* src  = (g < NG1) ? x : w;
  const int grow    = (g < NG1) ? g : g - NG1;
  const size_t sbase = (size_t)grow * GROUP + l * 4;

  const float4 v = *reinterpret_cast<const float4*>(src + sbase);

  const float mean = group32_sum(v.x + v.y + v.z + v.w) * (1.0f / 128.0f);
  const float d0 = v.x - mean, d1 = v.y - mean, d2 = v.z - mean, d3 = v.w - mean;
  const float var = group32_sum(d0 * d0 + d1 * d1 + d2 * d2 + d3 * d3) *
                    (1.0f / 127.0f);
  const float scale = (fabsf(mean) + 3.0f * sqrtf(var)) * alpha / 28.0f;
  const float rs4 = 0.25f / scale;          // to q/4 units

  float q0 = nearest_q4(v.x * rs4);
  float q1 = nearest_q4(v.y * rs4);
  float q2 = nearest_q4(v.z * rs4);
  float q3 = nearest_q4(v.w * rs4);
  // victim masking: outlier (|q/4|>8) zeroes its pair partner
  if (fabsf(q0) > 8.0f)      q1 = 0.0f;
  else if (fabsf(q1) > 8.0f) q0 = 0.0f;
  if (fabsf(q2) > 8.0f)      q3 = 0.0f;
  else if (fabsf(q3) > 8.0f) q2 = 0.0f;

  const int p = ((int)q0 & 255) | (((int)q1 & 255) << 8) |
                (((int)q2 & 255) << 16) | (((int)q3 & 255) << 24);
  reinterpret_cast<int*>(q8)[(size_t)g * 32 + l] = p;

  if (l == 0) {
    const float ss = 4.0f * scale;
    if (g < NG1) ssxT[(grow & 15) * 2048 + (grow >> 4)] = ss;
    else         sswT[(grow & 15) * 2048 + (grow >> 4)] = ss;
  }
}

// ---------------- GEMM: C = sum_g ssx*ssw*(int8 group dot) ----------------
// EXACT R9 geometry/schedule (proven 33.9 us): BM=128, BN=64, BK=128,
// 256 thr = 4 waves (wr,wc), wave tile 64x32, 2-deep pipeline vmcnt(6),
// XOR swizzle both-sides, XCD 4x16 chunks, no split-K.
// ONE change: DEFERRED SCALE-APPLY. Group j's iteration: issue 12 frag
// ds_reads -> apply scales to group j-1's acci (pure VALU on registers;
// scales were preloaded into regs during iter j-1, so no DS in-order-retire
// dependence) -> MFMA group j. Moves ~100 VALU ops/wave/group from the
// post-MFMA critical-path tail into the ds_read latency shadow. Explicit
// 2x unroll with named acciA/acciB banks (rule 20: static indexing).

__device__ __forceinline__ void gload_lds16(const int8_t* g, char* l) {
  __builtin_amdgcn_global_load_lds(
      (__attribute__((address_space(1))) uint32_t*)g,
      (__attribute__((address_space(3))) uint32_t*)l, 16, 0, 0);
}

__global__ __launch_bounds__(256, 2) void gemm_kernel(
    const int8_t* __restrict__ Aq, const int8_t* __restrict__ Bq,
    const float* __restrict__ ssxT, const float* __restrict__ sswT,
    float* __restrict__ C) {
  // 2 stages x (A 16K + B 8K) = 48 KB, + scales 12 KB = 60 KB (2 blocks/CU)
  __shared__ char lds_raw[2 * 24576 + 12288];
  float* ssx_l = (float*)(lds_raw + 49152);          // [16][128]
  float* ssw_l = (float*)(lds_raw + 49152 + 8192);   // [16][64]

  const int tid  = threadIdx.x;
  const int lane = tid & 63;
  const int wid  = tid >> 6;       // 0..3
  const int wr   = wid >> 1;       // 0..1 (64 rows)
  const int wc   = wid & 1;        // 0..1 (32 cols)
  const int r31  = lane & 31;
  const int hi   = lane >> 5;

  // XCD c owns bm in [(c&3)*4,+4), bn in [(c>>2)*16,+16): ~3 MB panels -> L2
  const int bid = blockIdx.x;
  const int c   = bid & 7;
  const int idx = bid >> 3;                   // 0..63
  const int bm  = ((c & 3) << 2) + (idx >> 4);    // 0..15
  const int bn  = ((c >> 2) << 4) + (idx & 15);   // 0..31

  const int8_t* gA = Aq + (size_t)(bm * 128) * DIM;
  const int8_t* gB = Bq + (size_t)(bn * 64) * DIM;

  auto stage = [&](char* buf, int g) {
#pragma unroll
    for (int i = 0; i < 4; ++i) {     // A: 128x128 i8 = 16 KB
      int P   = (i * 256 + tid) * 16;
      int row = P >> 7;
      int cb  = (P & 127) ^ ((row & 7) << 4);
      gload_lds16(gA + (size_t)row * DIM + g * 128 + cb, buf + P);
    }
#pragma unroll
    for (int i = 0; i < 2; ++i) {     // B: 64x128 i8 = 8 KB
      int P   = (i * 256 + tid) * 16;
      int row = P >> 7;
      int cb  = (P & 127) ^ ((row & 7) << 4);
      gload_lds16(gB + (size_t)row * DIM + g * 128 + cb, buf + 16384 + P);
    }
  };

  // ---- stage scale tables, then full drain (keeps manual vmcnt exact) ----
#pragma unroll
  for (int i = 0; i < 2; ++i) {       // ssx: 2048 floats
    int f = (i * 256 + tid) * 4;
    *reinterpret_cast<f32x4*>(&ssx_l[f]) =
        *reinterpret_cast<const f32x4*>(&ssxT[(f >> 7) * 2048 + bm * 128 + (f & 127)]);
  }
  {                                   // ssw: 1024 floats
    int f = tid * 4;
    *reinterpret_cast<f32x4*>(&ssw_l[f]) =
        *reinterpret_cast<const f32x4*>(&sswT[(f >> 6) * 2048 + bn * 64 + (f & 63)]);
  }
  __syncthreads();                    // drain scale loads + publish LDS

  f32x16 accf[2] = {};
  const i32x16 zacc = {};

  char* S0 = lds_raw;
  char* S1 = lds_raw + 24576;

  // scale registers for the group most recently MFMA'd (carried one iter)
  float sw_c = 0.0f;
  f32x4 sx_c[2][4];

  // apply scales to prev group's acci (pure VALU, register-only)
  auto apply = [&](const i32x16 prev[2]) {
#pragma unroll
    for (int mt = 0; mt < 2; ++mt)
#pragma unroll
      for (int q = 0; q < 4; ++q)
#pragma unroll
        for (int e = 0; e < 4; ++e)
          accf[mt][q * 4 + e] +=
              sx_c[mt][q][e] * (sw_c * (float)prev[mt][q * 4 + e]);
  };

  // one K-group step: stage j+1, sync, frag reads, apply(prev), load scales
  // for group j into sw_c/sx_c, MFMA group j into out[]
  auto step = [&](int j, i32x16 out[2], const i32x16 prev[2]) {
    if (j + 1 < NGK) {
      stage((j & 1) ? S0 : S1, j + 1);
      asm volatile("s_waitcnt vmcnt(6)" ::: "memory");   // group j's loads done
    } else {
      asm volatile("s_waitcnt vmcnt(0)" ::: "memory");
    }
    __builtin_amdgcn_s_barrier();
    const char* buf = (j & 1) ? S1 : S0;
    const char* cA = buf;
    const char* cB = buf + 16384;

    // issue all 12 fragment reads
    i32x4 af[4][2], bf[4];
#pragma unroll
    for (int ks = 0; ks < 4; ++ks) {
      const int cb = ks * 32 + hi * 16;
#pragma unroll
      for (int mt = 0; mt < 2; ++mt) {
        int row = wr * 64 + mt * 32 + r31;
        int pc  = cb ^ ((row & 7) << 4);
        af[ks][mt] = *reinterpret_cast<const i32x4*>(cA + (row << 7) + pc);
      }
      int row = wc * 32 + r31;
      int pc  = cb ^ ((row & 7) << 4);
      bf[ks] = *reinterpret_cast<const i32x4*>(cB + (row << 7) + pc);
    }

    // deferred scale-apply of group j-1 — fills the ds_read latency shadow
    if (j > 0) apply(prev);

    // load group j's scales into registers (used next step / tail)
    sw_c = ssw_l[j * 64 + wc * 32 + r31];
#pragma unroll
    for (int mt = 0; mt < 2; ++mt)
#pragma unroll
      for (int q = 0; q < 4; ++q)
        sx_c[mt][q] = *reinterpret_cast<const f32x4*>(
            &ssx_l[j * 128 + wr * 64 + mt * 32 + 8 * q + 4 * hi]);

    // integer MFMA for group j
    __builtin_amdgcn_s_setprio(1);
#pragma unroll
    for (int ks = 0; ks < 4; ++ks)
#pragma unroll
      for (int mt = 0; mt < 2; ++mt)
        out[mt] = __builtin_amdgcn_mfma_i32_32x32x32_i8(
            af[ks][mt], bf[ks], ks == 0 ? zacc : out[mt], 0, 0, 0);
    __builtin_amdgcn_s_setprio(0);
    __builtin_amdgcn_s_barrier();
  };

  i32x16 acciA[2], acciB[2];

  stage(S0, 0);
  for (int jj = 0; jj < NGK; jj += 2) {   // explicit 2x unroll: static banks
    step(jj + 0, acciA, acciB);           // group jj   -> A, applies B (jj-1)
    step(jj + 1, acciB, acciA);           // group jj+1 -> B, applies A (jj)
  }
  apply(acciB);                           // tail: group 15 (scales in sw_c/sx_c)

  // ---- direct C write (no split-K) ----
  const int crow0 = bm * 128 + wr * 64 + 4 * hi;
  const int ccol  = bn * 64 + wc * 32 + r31;
#pragma unroll
  for (int mt = 0; mt < 2; ++mt)
#pragma unroll
    for (int r = 0; r < 16; ++r) {
      int row = crow0 + mt * 32 + (r & 3) + 8 * (r >> 2);
      C[(size_t)row * DIM + ccol] = accf[mt][r];
    }
}

// ---------------- launch ----------------

extern "C" void kernel_launch(void* const* d_in, const int* in_sizes, int n_in,
                              void* d_out, int out_size, void* d_ws,
                              size_t ws_size, hipStream_t stream) {
  const float* x = (const float*)d_in[0];
  const float* w = (const float*)d_in[1];
  float* out = (float*)d_out;

  int8_t* qx   = (int8_t*)d_ws;                         // 4 MB
  int8_t* qw   = qx + (size_t)TOKENS * DIM;             // 4 MB
  float*  ssxT = (float*)(qw + (size_t)DIM * DIM);      // 128 KB
  float*  sswT = ssxT + NGK * 2048;                     // 128 KB

  const int ngroups = 2 * TOKENS * DIM / GROUP;         // 65536
  quant2_kernel<<<ngroups / 8, 256, 0, stream>>>(x, w, qx, ssxT, sswT);

  gemm_kernel<<<512, 256, 0, stream>>>(qx, qw, ssxT, sswT, out);
}